// Round 7
// baseline (151.805 us; speedup 1.0000x reference)
//
#include <hip/hip_runtime.h>
#include <hip/hip_fp16.h>
#include <math.h>

#define V_ 128
#define K_ 32
#define C_ 256
#define L_ 4
#define N_ 4096
#define F_ 16
#define E_ 8192
#define B_ 512
#define EPS_ 1e-6f

// ---------------------------------------------------------------------------
// Kernel 1: pack per-layer metadata.  For each (l,n,f):
//   e = sc[l,n,f]; c0,c1 = prod[l,e,:]; lw = log(sp+EPS) - log(sum_f(sp+EPS))
// stored as pidx[l][f][n] = uint2{ c0 | c1<<16 , bits(lw fp32) }.
// [l][f][n] layout -> mega kernel's loads are 512 B coalesced per wave.
// One thread per (l,n) row; grid = L*N/256 = 64 blocks.
// ---------------------------------------------------------------------------
__global__ __launch_bounds__(256) void pack_kernel(const float* __restrict__ sp,
                                                   const int* __restrict__ prod,
                                                   const int* __restrict__ sc,
                                                   uint2* __restrict__ pidx) {
    int idx = blockIdx.x * 256 + threadIdx.x;   // (l,n), L*N = 16384
    int l   = idx >> 12;                        // N = 4096
    int n   = idx & (N_ - 1);
    const float* row = sp + (size_t)idx * F_;
    float v[F_];
    float s = 0.f;
#pragma unroll
    for (int f = 0; f < F_; f++) { v[f] = row[f] + EPS_; s += v[f]; }
    float ls = __logf(s);
#pragma unroll
    for (int f = 0; f < F_; f++) {
        int e  = sc[(size_t)idx * F_ + f];
        int c0 = prod[((size_t)l * E_ + e) * 2 + 0];
        int c1 = prod[((size_t)l * E_ + e) * 2 + 1];
        float lw = __logf(v[f]) - ls;
        pidx[((size_t)l * F_ + f) * N_ + n] =
            make_uint2((unsigned)c0 | ((unsigned)c1 << 16), __float_as_uint(lw));
    }
}

// ---------------------------------------------------------------------------
// Kernel 2: per-row input normalizer.  ls[n] = log(sum_c(ip[n,:]+EPS)).
// One wave per row; grid = N/4 blocks x 256 threads.
// ---------------------------------------------------------------------------
__global__ __launch_bounds__(256) void row_ls_kernel(const float* __restrict__ ip,
                                                     float* __restrict__ ls) {
    int n    = blockIdx.x * 4 + (threadIdx.x >> 6);
    int lane = threadIdx.x & 63;
    const float* row = ip + (size_t)n * C_;
    float t = 0.f;
#pragma unroll
    for (int i = 0; i < 4; i++) t += row[lane + 64 * i] + EPS_;
#pragma unroll
    for (int off = 32; off; off >>= 1) t += __shfl_down(t, off, 64);
    if (lane == 0) ls[n] = __logf(t);
}

// ---------------------------------------------------------------------------
// Kernel 3: lroot = log(sum_n(rp+EPS)).  One block.
// ---------------------------------------------------------------------------
__global__ __launch_bounds__(256) void lroot_kernel(const float* __restrict__ rp,
                                                    float* __restrict__ lroot) {
    int tid = threadIdx.x;
    __shared__ float smem[4];
    float acc = 0.f;
    for (int i = tid; i < N_; i += 256) acc += rp[i] + EPS_;
#pragma unroll
    for (int off = 32; off; off >>= 1) acc += __shfl_down(acc, off, 64);
    if ((tid & 63) == 0) smem[tid >> 6] = acc;
    __syncthreads();
    if (tid == 0) lroot[0] = __logf(smem[0] + smem[1] + smem[2] + smem[3]);
}

// ---------------------------------------------------------------------------
// Kernel 4: the whole circuit for a 2-wide b-slice, entirely in LDS.
// Layers mix only n (never b) -> block owns b0,b1; nm lives in LDS
// (4096 x half2 = 16 KB, double-buffered = 32 KB); input -> 4 layers -> root
// with __syncthreads() between layers.  Intermediates never touch global.
// Global traffic: the packed index stream (identical for all blocks, L2-hot).
// Grid = B/2 = 256 blocks x 512 threads -> 1 block/CU.
// ---------------------------------------------------------------------------
__global__ __launch_bounds__(512) void mega_kernel(const float* __restrict__ ip,
                                                   const int* __restrict__ inputs,
                                                   const float* __restrict__ ls,
                                                   const float* __restrict__ rp,
                                                   const uint2* __restrict__ pidx,
                                                   const float* __restrict__ lrootp,
                                                   float* __restrict__ out) {
    __shared__ unsigned nm_s[2][N_];    // half2 (b0,b1) per n, double-buffered
    __shared__ float    red[8][4];
    int tid = threadIdx.x;
    int b0  = blockIdx.x * 2, b1 = b0 + 1;

    // ---- input layer: nm[0][n] = log(ip[n, x_b]+EPS) - ls[n] --------------
#pragma unroll
    for (int pass = 0; pass < N_ / 512; pass++) {
        int n  = pass * 512 + tid;
        int v  = n >> 5;                 // K = 32
        int x0 = inputs[b0 * V_ + v];
        int x1 = inputs[b1 * V_ + v];
        float lsn = ls[n];
        const float* row = ip + (size_t)n * C_;
        __half2 h = __floats2half2_rn(__logf(row[x0] + EPS_) - lsn,
                                      __logf(row[x1] + EPS_) - lsn);
        nm_s[0][n] = *reinterpret_cast<unsigned*>(&h);
    }
    __syncthreads();

    // ---- 4 sum-product layers in LDS --------------------------------------
    int cur = 0;
    for (int l = 0; l < L_; l++) {
        const uint2* P = pidx + (size_t)l * F_ * N_;
#pragma unroll 2
        for (int pass = 0; pass < N_ / 512; pass++) {
            int n = pass * 512 + tid;
            uint2 p[F_];
#pragma unroll
            for (int f = 0; f < F_; f++) p[f] = P[f * N_ + n];
            float2 a[F_];
            float mx = -1e30f, my = -1e30f;
#pragma unroll
            for (int f = 0; f < F_; f++) {
                unsigned u0 = nm_s[cur][p[f].x & 0xffff];
                unsigned u1 = nm_s[cur][p[f].x >> 16];
                float2 x0 = __half22float2(*reinterpret_cast<__half2*>(&u0));
                float2 x1 = __half22float2(*reinterpret_cast<__half2*>(&u1));
                float  w  = __uint_as_float(p[f].y);
                a[f].x = x0.x + x1.x + w;
                a[f].y = x0.y + x1.y + w;
                mx = fmaxf(mx, a[f].x);
                my = fmaxf(my, a[f].y);
            }
            float sx = 0.f, sy = 0.f;
#pragma unroll
            for (int f = 0; f < F_; f++) {
                sx += __expf(a[f].x - mx);
                sy += __expf(a[f].y - my);
            }
            __half2 h = __floats2half2_rn(mx + __logf(sx), my + __logf(sy));
            nm_s[cur ^ 1][n] = *reinterpret_cast<unsigned*>(&h);
        }
        __syncthreads();
        cur ^= 1;
    }

    // ---- root: LSE over all n for b0,b1 ------------------------------------
    float m0 = -1e30f, s0 = 0.f, m1 = -1e30f, s1 = 0.f;
#pragma unroll
    for (int pass = 0; pass < N_ / 512; pass++) {
        int n = pass * 512 + tid;
        unsigned u = nm_s[cur][n];
        float2 x  = __half22float2(*reinterpret_cast<__half2*>(&u));
        float lrn = __logf(rp[n] + EPS_);
        float a0 = x.x + lrn, a1 = x.y + lrn;
        float M0 = fmaxf(m0, a0);
        s0 = s0 * __expf(m0 - M0) + __expf(a0 - M0); m0 = M0;
        float M1 = fmaxf(m1, a1);
        s1 = s1 * __expf(m1 - M1) + __expf(a1 - M1); m1 = M1;
    }
    // wave-level LSE merge
#pragma unroll
    for (int off = 32; off; off >>= 1) {
        float mm = __shfl_down(m0, off, 64), ss = __shfl_down(s0, off, 64);
        float M  = fmaxf(m0, mm);
        s0 = s0 * __expf(m0 - M) + ss * __expf(mm - M); m0 = M;
        mm = __shfl_down(m1, off, 64); ss = __shfl_down(s1, off, 64);
        M  = fmaxf(m1, mm);
        s1 = s1 * __expf(m1 - M) + ss * __expf(mm - M); m1 = M;
    }
    int w = tid >> 6, lane = tid & 63;
    if (lane == 0) { red[w][0] = m0; red[w][1] = s0; red[w][2] = m1; red[w][3] = s1; }
    __syncthreads();
    if (tid == 0) {
        float M0 = red[0][0], S0 = red[0][1], M1 = red[0][2], S1 = red[0][3];
#pragma unroll
        for (int i = 1; i < 8; i++) {
            float mm = red[i][0], ss = red[i][1];
            float M  = fmaxf(M0, mm);
            S0 = S0 * __expf(M0 - M) + ss * __expf(mm - M); M0 = M;
            mm = red[i][2]; ss = red[i][3];
            M  = fmaxf(M1, mm);
            S1 = S1 * __expf(M1 - M) + ss * __expf(mm - M); M1 = M;
        }
        float lroot = lrootp[0];
        out[b0] = M0 + __logf(S0) - lroot;
        out[b1] = M1 + __logf(S1) - lroot;
    }
}

extern "C" void kernel_launch(void* const* d_in, const int* in_sizes, int n_in,
                              void* d_out, int out_size, void* d_ws, size_t ws_size,
                              hipStream_t stream) {
    const int*   inputs = (const int*)d_in[0];     // (B, V) int32
    const int*   prod   = (const int*)d_in[1];     // (L, E, 2) int32
    const int*   sc     = (const int*)d_in[2];     // (L, N, F) int32
    const float* ip     = (const float*)d_in[3];   // (V, K, C) f32
    const float* sp     = (const float*)d_in[4];   // (L, N, F) f32
    const float* rp     = (const float*)d_in[5];   // (N,) f32
    float* out = (float*)d_out;                    // (B,) f32

    uint2* pidx  = (uint2*)d_ws;                   // L*F*N uint2 (2 MB), 8B-aligned
    float* ls    = (float*)(pidx + (size_t)L_ * F_ * N_);  // N floats
    float* lroot = ls + N_;                                // 1 float

    pack_kernel<<<(L_ * N_) / 256, 256, 0, stream>>>(sp, prod, sc, pidx);
    row_ls_kernel<<<N_ / 4, 256, 0, stream>>>(ip, ls);
    lroot_kernel<<<1, 256, 0, stream>>>(rp, lroot);
    mega_kernel<<<B_ / 2, 512, 0, stream>>>(ip, inputs, ls, rp, pidx, lroot, out);
}

// Round 9
// 114.601 us; speedup vs baseline: 1.3246x; 1.3246x over previous
//
#include <hip/hip_runtime.h>
#include <hip/hip_fp16.h>
#include <math.h>

#define V_ 128
#define K_ 32
#define C_ 256
#define L_ 4
#define N_ 4096
#define F_ 16
#define E_ 8192
#define B_ 512
#define EPS_ 1e-6f

__device__ __forceinline__ __half2 u2h(unsigned u) {
    __half2 h; *reinterpret_cast<unsigned*>(&h) = u; return h;
}
__device__ __forceinline__ unsigned h2u(__half2 h) {
    return *reinterpret_cast<unsigned*>(&h);
}
// ROCm has no __hmax2; exact packed max via lossless half->float round-trip.
__device__ __forceinline__ __half2 hmax2(__half2 a, __half2 b) {
    float2 fa = __half22float2(a), fb = __half22float2(b);
    return __floats2half2_rn(fmaxf(fa.x, fb.x), fmaxf(fa.y, fb.y));
}

// ---------------------------------------------------------------------------
// Fused prep kernel (one launch, 1089 blocks x 256 threads):
//  blocks [0,64):    pack — for each (l,n): linear weights w_f = (sp+EPS)/Σ,
//                    child ids -> PU[l][f][n] = c0|c1<<16, PW[l][f][n] = w_f.
//  blocks [64,1088): inv_row[n] = 1/Σ_c(ip[n,c]+EPS)   (4 rows/block)
//  block 1088:       lrpsum = log(Σ_n(rp[n]+EPS))
// ---------------------------------------------------------------------------
__global__ __launch_bounds__(256) void prep_kernel(const float* __restrict__ sp,
                                                   const int* __restrict__ prod,
                                                   const int* __restrict__ sc,
                                                   const float* __restrict__ ip,
                                                   const float* __restrict__ rp,
                                                   unsigned* __restrict__ PU,
                                                   __half* __restrict__ PW,
                                                   float* __restrict__ inv_row,
                                                   float* __restrict__ lrpsum) {
    int blk = blockIdx.x;
    int tid = threadIdx.x;
    if (blk < 64) {
        int idx = blk * 256 + tid;          // (l,n), L*N = 16384
        int l   = idx >> 12;
        int n   = idx & (N_ - 1);
        const float4* row4 = (const float4*)(sp + (size_t)idx * F_);
        float v[F_];
        float s = 0.f;
#pragma unroll
        for (int q = 0; q < 4; q++) {
            float4 r = row4[q];
            v[4*q+0] = r.x + EPS_; v[4*q+1] = r.y + EPS_;
            v[4*q+2] = r.z + EPS_; v[4*q+3] = r.w + EPS_;
            s += v[4*q+0] + v[4*q+1] + v[4*q+2] + v[4*q+3];
        }
        float inv = 1.f / s;
        const int* scr = sc + (size_t)idx * F_;
#pragma unroll
        for (int f = 0; f < F_; f++) {
            int  e = scr[f];
            int2 c = ((const int2*)prod)[(size_t)l * E_ + e];
            PU[((size_t)l * F_ + f) * N_ + n] = (unsigned)c.x | ((unsigned)c.y << 16);
            PW[((size_t)l * F_ + f) * N_ + n] = __float2half(v[f] * inv);
        }
    } else if (blk < 64 + 1024) {
        int rblk = blk - 64;
        int n    = rblk * 4 + (tid >> 6);
        int lane = tid & 63;
        const float* row = ip + (size_t)n * C_;
        float t = 0.f;
#pragma unroll
        for (int i = 0; i < 4; i++) t += row[lane + 64 * i] + EPS_;
#pragma unroll
        for (int off = 32; off; off >>= 1) t += __shfl_down(t, off, 64);
        if (lane == 0) inv_row[n] = 1.f / t;
    } else {
        __shared__ float smem[4];
        float acc = 0.f;
        for (int i = tid; i < N_; i += 256) acc += rp[i] + EPS_;
#pragma unroll
        for (int off = 32; off; off >>= 1) acc += __shfl_down(acc, off, 64);
        if ((tid & 63) == 0) smem[tid >> 6] = acc;
        __syncthreads();
        if (tid == 0) lrpsum[0] = __logf(smem[0] + smem[1] + smem[2] + smem[3]);
    }
}

// ---------------------------------------------------------------------------
// Mega kernel: whole circuit per 2-wide b-slice, scaled-LINEAR domain in LDS.
// Layers mix only n -> block owns (b0,b1); nm = half2[4096] (16 KB, single
// buffer: layer output held in regs across the max-reduction barrier, then
// written back renormalized).  Per (n,f): 2 LDS gathers + pk_mul + pk_fma —
// ZERO exp/log in the hot loop.  Per-b log-scale sigma tracked exactly
// (sigma' = 2*sigma - log(applied rounded inverse scale)).
// Grid = B/2 = 256 blocks x 1024 threads (16 waves/CU).
// ---------------------------------------------------------------------------
__global__ __launch_bounds__(1024) void mega_kernel(const float* __restrict__ ip,
                                                    const int* __restrict__ inputs,
                                                    const float* __restrict__ inv_row,
                                                    const float* __restrict__ rp,
                                                    const unsigned* __restrict__ PU,
                                                    const __half* __restrict__ PW,
                                                    const float* __restrict__ lrpsum,
                                                    float* __restrict__ out) {
    __shared__ unsigned nm[N_];        // half2 (b0,b1) per n
    __shared__ unsigned redm[16];
    __shared__ float    redf[32];
    int tid  = threadIdx.x;
    int lane = tid & 63;
    int w    = tid >> 6;
    int b0   = blockIdx.x * 2, b1 = b0 + 1;

    // ---- input layer: linear u = (ip[n,x]+EPS)/rowsum, renorm by per-b max
    float2 u[4];
    float mx0 = 0.f, mx1 = 0.f;
#pragma unroll
    for (int p = 0; p < 4; p++) {
        int n  = p * 1024 + tid;
        int v  = n >> 5;                       // K = 32
        int x0 = inputs[b0 * V_ + v];
        int x1 = inputs[b1 * V_ + v];
        float invr = inv_row[n];
        u[p].x = (ip[(size_t)n * C_ + x0] + EPS_) * invr;
        u[p].y = (ip[(size_t)n * C_ + x1] + EPS_) * invr;
        mx0 = fmaxf(mx0, u[p].x);
        mx1 = fmaxf(mx1, u[p].y);
    }
#pragma unroll
    for (int off = 32; off; off >>= 1) {
        mx0 = fmaxf(mx0, __shfl_down(mx0, off, 64));
        mx1 = fmaxf(mx1, __shfl_down(mx1, off, 64));
    }
    if (lane == 0) { redf[w] = mx0; redf[16 + w] = mx1; }
    __syncthreads();
    float m0 = redf[0], m1 = redf[16];
#pragma unroll
    for (int i = 1; i < 16; i++) { m0 = fmaxf(m0, redf[i]); m1 = fmaxf(m1, redf[16 + i]); }
    float inv0 = 1.f / m0, inv1 = 1.f / m1;
    float sg0 = -__logf(inv0), sg1 = -__logf(inv1);   // true = stored * e^sigma
#pragma unroll
    for (int p = 0; p < 4; p++)
        nm[p * 1024 + tid] = h2u(__floats2half2_rn(u[p].x * inv0, u[p].y * inv1));
    __syncthreads();

    // ---- layers 0..2: linear sum-product + renorm
    for (int l = 0; l < L_ - 1; l++) {
        const unsigned* pu = PU + (size_t)l * F_ * N_;
        const __half*   pw = PW + (size_t)l * F_ * N_;
        unsigned o[4];
        __half2  hm = u2h(0u);
#pragma unroll
        for (int p = 0; p < 4; p++) {
            int n = p * 1024 + tid;
            unsigned pk[F_];
            __half   wv[F_];
#pragma unroll
            for (int f = 0; f < F_; f++) { pk[f] = pu[f * N_ + n]; wv[f] = pw[f * N_ + n]; }
            __half2 acc = u2h(0u);
#pragma unroll
            for (int f = 0; f < F_; f++) {
                __half2 a = u2h(nm[pk[f] & 0xffff]);
                __half2 b = u2h(nm[pk[f] >> 16]);
                acc = __hfma2(__hmul2(a, b), __half2half2(wv[f]), acc);
            }
            o[p] = h2u(acc);
            hm   = hmax2(hm, acc);
        }
        // block max reduce (barrier also closes all reads of nm)
#pragma unroll
        for (int off = 32; off; off >>= 1)
            hm = hmax2(hm, u2h(__shfl_down(h2u(hm), off, 64)));
        if (lane == 0) redm[w] = h2u(hm);
        __syncthreads();
        __half2 M = u2h(redm[0]);
#pragma unroll
        for (int i = 1; i < 16; i++) M = hmax2(M, u2h(redm[i]));
        float M0 = __half2float(__low2half(M)), M1 = __half2float(__high2half(M));
        __half2 hi = __floats2half2_rn(1.f / M0, 1.f / M1);
        float ai0 = __half2float(__low2half(hi)), ai1 = __half2float(__high2half(hi));
        sg0 = 2.f * sg0 - __logf(ai0);
        sg1 = 2.f * sg1 - __logf(ai1);
#pragma unroll
        for (int p = 0; p < 4; p++)
            nm[p * 1024 + tid] = h2u(__hmul2(u2h(o[p]), hi));
        __syncthreads();
    }

    // ---- layer 3 (no renorm, kept in regs) fused with root dot-product
    {
        const unsigned* pu = PU + (size_t)(L_ - 1) * F_ * N_;
        const __half*   pw = PW + (size_t)(L_ - 1) * F_ * N_;
        float S0 = 0.f, S1 = 0.f;
#pragma unroll
        for (int p = 0; p < 4; p++) {
            int n = p * 1024 + tid;
            unsigned pk[F_];
            __half   wv[F_];
#pragma unroll
            for (int f = 0; f < F_; f++) { pk[f] = pu[f * N_ + n]; wv[f] = pw[f * N_ + n]; }
            __half2 acc = u2h(0u);
#pragma unroll
            for (int f = 0; f < F_; f++) {
                __half2 a = u2h(nm[pk[f] & 0xffff]);
                __half2 b = u2h(nm[pk[f] >> 16]);
                acc = __hfma2(__hmul2(a, b), __half2half2(wv[f]), acc);
            }
            float2 vv = __half22float2(acc);
            float  r  = rp[n] + EPS_;
            S0 += r * vv.x;
            S1 += r * vv.y;
        }
        float sgf0 = 2.f * sg0, sgf1 = 2.f * sg1;
#pragma unroll
        for (int off = 32; off; off >>= 1) {
            S0 += __shfl_down(S0, off, 64);
            S1 += __shfl_down(S1, off, 64);
        }
        if (lane == 0) { redf[w] = S0; redf[16 + w] = S1; }
        __syncthreads();
        if (tid == 0) {
            float s0 = 0.f, s1 = 0.f;
#pragma unroll
            for (int i = 0; i < 16; i++) { s0 += redf[i]; s1 += redf[16 + i]; }
            float lr = lrpsum[0];
            out[b0] = __logf(s0) + sgf0 - lr;
            out[b1] = __logf(s1) + sgf1 - lr;
        }
    }
}

extern "C" void kernel_launch(void* const* d_in, const int* in_sizes, int n_in,
                              void* d_out, int out_size, void* d_ws, size_t ws_size,
                              hipStream_t stream) {
    const int*   inputs = (const int*)d_in[0];     // (B, V) int32
    const int*   prod   = (const int*)d_in[1];     // (L, E, 2) int32
    const int*   sc     = (const int*)d_in[2];     // (L, N, F) int32
    const float* ip     = (const float*)d_in[3];   // (V, K, C) f32
    const float* sp     = (const float*)d_in[4];   // (L, N, F) f32
    const float* rp     = (const float*)d_in[5];   // (N,) f32
    float* out = (float*)d_out;                    // (B,) f32

    unsigned* PU      = (unsigned*)d_ws;                    // L*F*N u32 (1 MB)
    __half*   PW      = (__half*)(PU + (size_t)L_ * F_ * N_); // L*F*N half (0.5 MB)
    float*    inv_row = (float*)(PW + (size_t)L_ * F_ * N_);  // N floats
    float*    lrpsum  = inv_row + N_;                         // 1 float

    prep_kernel<<<64 + 1024 + 1, 256, 0, stream>>>(sp, prod, sc, ip, rp,
                                                   PU, PW, inv_row, lrpsum);
    mega_kernel<<<B_ / 2, 1024, 0, stream>>>(ip, inputs, inv_row, rp,
                                             PU, PW, lrpsum, out);
}

// Round 10
// 108.042 us; speedup vs baseline: 1.4051x; 1.0607x over previous
//
#include <hip/hip_runtime.h>
#include <hip/hip_fp16.h>
#include <math.h>

#define V_ 128
#define K_ 32
#define C_ 256
#define L_ 4
#define N_ 4096
#define F_ 16
#define E_ 8192
#define B_ 512
#define EPS_ 1e-6f

__device__ __forceinline__ __half2 u2h(unsigned u) {
    __half2 h; *reinterpret_cast<unsigned*>(&h) = u; return h;
}
__device__ __forceinline__ unsigned h2u(__half2 h) {
    return *reinterpret_cast<unsigned*>(&h);
}
__device__ __forceinline__ __half b2h(unsigned short u) {
    __half h; *reinterpret_cast<unsigned short*>(&h) = u; return h;
}
__device__ __forceinline__ unsigned short h2b(__half h) {
    return *reinterpret_cast<unsigned short*>(&h);
}
// ROCm has no __hmax2; exact packed max via lossless half->float round-trip.
__device__ __forceinline__ __half2 hmax2(__half2 a, __half2 b) {
    float2 fa = __half22float2(a), fb = __half22float2(b);
    return __floats2half2_rn(fmaxf(fa.x, fb.x), fmaxf(fa.y, fb.y));
}

// ---------------------------------------------------------------------------
// Fused prep kernel (one launch, 1217 blocks x 256 threads):
//  [0,64):      PIW[l][f][n] = sc16 | half_bits(w_f)<<16, w_f = (sp+EPS)/Σ_f
//  [64,192):    PP[l][e] = c0 | c1<<16  (product children, L*E entries)
//  [192,1216):  inv_row[n] = 1/Σ_c(ip[n,c]+EPS)   (4 rows/block)
//  block 1216:  lrpsum = log(Σ_n(rp[n]+EPS))
// ---------------------------------------------------------------------------
__global__ __launch_bounds__(256) void prep_kernel(const float* __restrict__ sp,
                                                   const int* __restrict__ prod,
                                                   const int* __restrict__ sc,
                                                   const float* __restrict__ ip,
                                                   const float* __restrict__ rp,
                                                   unsigned* __restrict__ PIW,
                                                   unsigned* __restrict__ PP,
                                                   float* __restrict__ inv_row,
                                                   float* __restrict__ lrpsum) {
    int blk = blockIdx.x;
    int tid = threadIdx.x;
    if (blk < 64) {
        int idx = blk * 256 + tid;          // (l,n), L*N = 16384
        int l   = idx >> 12;
        int n   = idx & (N_ - 1);
        const float4* row4 = (const float4*)(sp + (size_t)idx * F_);
        float v[F_];
        float s = 0.f;
#pragma unroll
        for (int q = 0; q < 4; q++) {
            float4 r = row4[q];
            v[4*q+0] = r.x + EPS_; v[4*q+1] = r.y + EPS_;
            v[4*q+2] = r.z + EPS_; v[4*q+3] = r.w + EPS_;
            s += v[4*q+0] + v[4*q+1] + v[4*q+2] + v[4*q+3];
        }
        float inv = 1.f / s;
        const int* scr = sc + (size_t)idx * F_;
#pragma unroll
        for (int f = 0; f < F_; f++) {
            unsigned wbits = h2b(__float2half(v[f] * inv));
            PIW[((size_t)l * F_ + f) * N_ + n] =
                (unsigned)(unsigned short)scr[f] | (wbits << 16);
        }
    } else if (blk < 192) {
        int idx = (blk - 64) * 256 + tid;   // (l,e), L*E = 32768
        int2 c  = ((const int2*)prod)[idx];
        PP[idx] = (unsigned)c.x | ((unsigned)c.y << 16);
    } else if (blk < 192 + 1024) {
        int rblk = blk - 192;
        int n    = rblk * 4 + (tid >> 6);
        int lane = tid & 63;
        const float* row = ip + (size_t)n * C_;
        float t = 0.f;
#pragma unroll
        for (int i = 0; i < 4; i++) t += row[lane + 64 * i] + EPS_;
#pragma unroll
        for (int off = 32; off; off >>= 1) t += __shfl_down(t, off, 64);
        if (lane == 0) inv_row[n] = 1.f / t;
    } else {
        __shared__ float smem[4];
        float acc = 0.f;
        for (int i = tid; i < N_; i += 256) acc += rp[i] + EPS_;
#pragma unroll
        for (int off = 32; off; off >>= 1) acc += __shfl_down(acc, off, 64);
        if ((tid & 63) == 0) smem[tid >> 6] = acc;
        __syncthreads();
        if (tid == 0) lrpsum[0] = __logf(smem[0] + smem[1] + smem[2] + smem[3]);
    }
}

// ---------------------------------------------------------------------------
// Mega kernel: whole circuit per 2-wide b-slice, scaled-linear in LDS, with
// product-node MEMOIZATION: em[e] = nm[c0]*nm[c1] computed once per e (E=8192,
// 16384 gathers + 8192 seq writes), then the sum stage gathers em[sc] once
// per (n,f) (65536) — 82k lane-gathers/layer vs 131k unmemoized (1.6x cut on
// the LDS pipe, which R9 counters show is the bottleneck at ~37 of 47.8 us).
// Sum-stage index+weight packed in one u32. sigma bookkeeping exact.
// Grid = B/2 = 256 blocks x 1024 threads; LDS = 16+32 KB.
// ---------------------------------------------------------------------------
__global__ __launch_bounds__(1024) void mega_kernel(const float* __restrict__ ip,
                                                    const int* __restrict__ inputs,
                                                    const float* __restrict__ inv_row,
                                                    const float* __restrict__ rp,
                                                    const unsigned* __restrict__ PIW,
                                                    const unsigned* __restrict__ PP,
                                                    const float* __restrict__ lrpsum,
                                                    float* __restrict__ out) {
    __shared__ unsigned nm[N_];        // half2 (b0,b1) per sum node   (16 KB)
    __shared__ unsigned em[E_];        // half2 (b0,b1) per product    (32 KB)
    __shared__ unsigned redm[16];
    __shared__ float    redf[32];
    int tid  = threadIdx.x;
    int lane = tid & 63;
    int w    = tid >> 6;
    int b0   = blockIdx.x * 2, b1 = b0 + 1;

    // ---- input layer: linear u = (ip[n,x]+EPS)/rowsum, renorm by per-b max
    float2 u[4];
    float mx0 = 0.f, mx1 = 0.f;
#pragma unroll
    for (int p = 0; p < 4; p++) {
        int n  = p * 1024 + tid;
        int v  = n >> 5;                       // K = 32
        int x0 = inputs[b0 * V_ + v];
        int x1 = inputs[b1 * V_ + v];
        float invr = inv_row[n];
        u[p].x = (ip[(size_t)n * C_ + x0] + EPS_) * invr;
        u[p].y = (ip[(size_t)n * C_ + x1] + EPS_) * invr;
        mx0 = fmaxf(mx0, u[p].x);
        mx1 = fmaxf(mx1, u[p].y);
    }
#pragma unroll
    for (int off = 32; off; off >>= 1) {
        mx0 = fmaxf(mx0, __shfl_down(mx0, off, 64));
        mx1 = fmaxf(mx1, __shfl_down(mx1, off, 64));
    }
    if (lane == 0) { redf[w] = mx0; redf[16 + w] = mx1; }
    __syncthreads();
    float m0 = redf[0], m1 = redf[16];
#pragma unroll
    for (int i = 1; i < 16; i++) { m0 = fmaxf(m0, redf[i]); m1 = fmaxf(m1, redf[16 + i]); }
    float inv0 = 1.f / m0, inv1 = 1.f / m1;
    float sg0 = -__logf(inv0), sg1 = -__logf(inv1);   // true = stored * e^sigma
#pragma unroll
    for (int p = 0; p < 4; p++)
        nm[p * 1024 + tid] = h2u(__floats2half2_rn(u[p].x * inv0, u[p].y * inv1));
    __syncthreads();

    // ---- layers 0..2: memoized product stage, then sum stage, then renorm
    for (int l = 0; l < L_ - 1; l++) {
        const unsigned* pp = PP + (size_t)l * E_;
#pragma unroll
        for (int p = 0; p < 8; p++) {
            int e = p * 1024 + tid;
            unsigned c = pp[e];
            em[e] = h2u(__hmul2(u2h(nm[c & 0xffff]), u2h(nm[c >> 16])));
        }
        __syncthreads();

        const unsigned* piw = PIW + (size_t)l * F_ * N_;
        unsigned o[4];
        __half2  hm = u2h(0u);
#pragma unroll
        for (int p = 0; p < 4; p++) {
            int n = p * 1024 + tid;
            unsigned q[F_];
#pragma unroll
            for (int f = 0; f < F_; f++) q[f] = piw[f * N_ + n];
            __half2 acc = u2h(0u);
#pragma unroll
            for (int f = 0; f < F_; f++)
                acc = __hfma2(u2h(em[q[f] & 0xffff]),
                              __half2half2(b2h((unsigned short)(q[f] >> 16))), acc);
            o[p] = h2u(acc);
            hm   = hmax2(hm, acc);
        }
        // block max reduce (this barrier also closes all reads of em)
#pragma unroll
        for (int off = 32; off; off >>= 1)
            hm = hmax2(hm, u2h(__shfl_down(h2u(hm), off, 64)));
        if (lane == 0) redm[w] = h2u(hm);
        __syncthreads();
        __half2 M = u2h(redm[0]);
#pragma unroll
        for (int i = 1; i < 16; i++) M = hmax2(M, u2h(redm[i]));
        float M0 = __half2float(__low2half(M)), M1 = __half2float(__high2half(M));
        __half2 hi = __floats2half2_rn(1.f / M0, 1.f / M1);
        float ai0 = __half2float(__low2half(hi)), ai1 = __half2float(__high2half(hi));
        sg0 = 2.f * sg0 - __logf(ai0);
        sg1 = 2.f * sg1 - __logf(ai1);
#pragma unroll
        for (int p = 0; p < 4; p++)
            nm[p * 1024 + tid] = h2u(__hmul2(u2h(o[p]), hi));
        __syncthreads();
    }

    // ---- layer 3 (no renorm) fused with root dot-product
    {
        const unsigned* pp = PP + (size_t)(L_ - 1) * E_;
#pragma unroll
        for (int p = 0; p < 8; p++) {
            int e = p * 1024 + tid;
            unsigned c = pp[e];
            em[e] = h2u(__hmul2(u2h(nm[c & 0xffff]), u2h(nm[c >> 16])));
        }
        __syncthreads();

        const unsigned* piw = PIW + (size_t)(L_ - 1) * F_ * N_;
        float S0 = 0.f, S1 = 0.f;
#pragma unroll
        for (int p = 0; p < 4; p++) {
            int n = p * 1024 + tid;
            unsigned q[F_];
#pragma unroll
            for (int f = 0; f < F_; f++) q[f] = piw[f * N_ + n];
            __half2 acc = u2h(0u);
#pragma unroll
            for (int f = 0; f < F_; f++)
                acc = __hfma2(u2h(em[q[f] & 0xffff]),
                              __half2half2(b2h((unsigned short)(q[f] >> 16))), acc);
            float2 vv = __half22float2(acc);
            float  r  = rp[n] + EPS_;
            S0 += r * vv.x;
            S1 += r * vv.y;
        }
        float sgf0 = 2.f * sg0, sgf1 = 2.f * sg1;
#pragma unroll
        for (int off = 32; off; off >>= 1) {
            S0 += __shfl_down(S0, off, 64);
            S1 += __shfl_down(S1, off, 64);
        }
        if (lane == 0) { redf[w] = S0; redf[16 + w] = S1; }
        __syncthreads();
        if (tid == 0) {
            float s0 = 0.f, s1 = 0.f;
#pragma unroll
            for (int i = 0; i < 16; i++) { s0 += redf[i]; s1 += redf[16 + i]; }
            float lr = lrpsum[0];
            out[b0] = __logf(s0) + sgf0 - lr;
            out[b1] = __logf(s1) + sgf1 - lr;
        }
    }
}

extern "C" void kernel_launch(void* const* d_in, const int* in_sizes, int n_in,
                              void* d_out, int out_size, void* d_ws, size_t ws_size,
                              hipStream_t stream) {
    const int*   inputs = (const int*)d_in[0];     // (B, V) int32
    const int*   prod   = (const int*)d_in[1];     // (L, E, 2) int32
    const int*   sc     = (const int*)d_in[2];     // (L, N, F) int32
    const float* ip     = (const float*)d_in[3];   // (V, K, C) f32
    const float* sp     = (const float*)d_in[4];   // (L, N, F) f32
    const float* rp     = (const float*)d_in[5];   // (N,) f32
    float* out = (float*)d_out;                    // (B,) f32

    unsigned* PIW     = (unsigned*)d_ws;                     // L*F*N u32 (1 MB)
    unsigned* PP      = PIW + (size_t)L_ * F_ * N_;          // L*E u32 (128 KB)
    float*    inv_row = (float*)(PP + (size_t)L_ * E_);      // N floats
    float*    lrpsum  = inv_row + N_;                        // 1 float

    prep_kernel<<<64 + 128 + 1024 + 1, 256, 0, stream>>>(sp, prod, sc, ip, rp,
                                                         PIW, PP, inv_row, lrpsum);
    mega_kernel<<<B_ / 2, 1024, 0, stream>>>(ip, inputs, inv_row, rp,
                                             PIW, PP, lrpsum, out);
}

// Round 11
// 106.946 us; speedup vs baseline: 1.4195x; 1.0102x over previous
//
#include <hip/hip_runtime.h>
#include <hip/hip_fp16.h>
#include <math.h>

#define V_ 128
#define K_ 32
#define C_ 256
#define L_ 4
#define N_ 4096
#define F_ 16
#define E_ 8192
#define B_ 512
#define EPS_ 1e-6f

__device__ __forceinline__ __half2 u2h(unsigned u) {
    __half2 h; *reinterpret_cast<unsigned*>(&h) = u; return h;
}
__device__ __forceinline__ unsigned h2u(__half2 h) {
    return *reinterpret_cast<unsigned*>(&h);
}
__device__ __forceinline__ __half b2h(unsigned short u) {
    __half h; *reinterpret_cast<unsigned short*>(&h) = u; return h;
}
__device__ __forceinline__ unsigned short h2b(__half h) {
    return *reinterpret_cast<unsigned short*>(&h);
}
// ROCm has no __hmax2; exact packed max via lossless half->float round-trip.
__device__ __forceinline__ __half2 hmax2(__half2 a, __half2 b) {
    float2 fa = __half22float2(a), fb = __half22float2(b);
    return __floats2half2_rn(fmaxf(fa.x, fb.x), fmaxf(fa.y, fb.y));
}

// ---------------------------------------------------------------------------
// Fused prep kernel (one launch, 1217 blocks x 256 threads):
//  [0,64):      PIW[l][n][f] = sc16 | half_bits(w_f)<<16, w_f = (sp+EPS)/Σ_f
//               ([l][n][f] layout -> mega reads 4x uint4 per (n,layer))
//  [64,192):    PP[l][e] = c0 | c1<<16  (product children, L*E entries)
//  [192,1216):  inv_row[n] = 1/Σ_c(ip[n,c]+EPS)   (4 rows/block)
//  block 1216:  lrpsum = log(Σ_n(rp[n]+EPS))
// ---------------------------------------------------------------------------
__global__ __launch_bounds__(256) void prep_kernel(const float* __restrict__ sp,
                                                   const int* __restrict__ prod,
                                                   const int* __restrict__ sc,
                                                   const float* __restrict__ ip,
                                                   const float* __restrict__ rp,
                                                   unsigned* __restrict__ PIW,
                                                   unsigned* __restrict__ PP,
                                                   float* __restrict__ inv_row,
                                                   float* __restrict__ lrpsum) {
    int blk = blockIdx.x;
    int tid = threadIdx.x;
    if (blk < 64) {
        int idx = blk * 256 + tid;          // (l,n), L*N = 16384
        const float4* row4 = (const float4*)(sp + (size_t)idx * F_);
        float v[F_];
        float s = 0.f;
#pragma unroll
        for (int q = 0; q < 4; q++) {
            float4 r = row4[q];
            v[4*q+0] = r.x + EPS_; v[4*q+1] = r.y + EPS_;
            v[4*q+2] = r.z + EPS_; v[4*q+3] = r.w + EPS_;
            s += v[4*q+0] + v[4*q+1] + v[4*q+2] + v[4*q+3];
        }
        float inv = 1.f / s;
        const int* scr = sc + (size_t)idx * F_;
        unsigned* dst  = PIW + (size_t)idx * F_;
#pragma unroll
        for (int f = 0; f < F_; f++) {
            unsigned wbits = h2b(__float2half(v[f] * inv));
            dst[f] = (unsigned)(unsigned short)scr[f] | (wbits << 16);
        }
    } else if (blk < 192) {
        int idx = (blk - 64) * 256 + tid;   // (l,e), L*E = 32768
        int2 c  = ((const int2*)prod)[idx];
        PP[idx] = (unsigned)c.x | ((unsigned)c.y << 16);
    } else if (blk < 192 + 1024) {
        int rblk = blk - 192;
        int n    = rblk * 4 + (tid >> 6);
        int lane = tid & 63;
        const float* row = ip + (size_t)n * C_;
        float t = 0.f;
#pragma unroll
        for (int i = 0; i < 4; i++) t += row[lane + 64 * i] + EPS_;
#pragma unroll
        for (int off = 32; off; off >>= 1) t += __shfl_down(t, off, 64);
        if (lane == 0) inv_row[n] = 1.f / t;
    } else {
        __shared__ float smem[4];
        float acc = 0.f;
        for (int i = tid; i < N_; i += 256) acc += rp[i] + EPS_;
#pragma unroll
        for (int off = 32; off; off >>= 1) acc += __shfl_down(acc, off, 64);
        if ((tid & 63) == 0) smem[tid >> 6] = acc;
        __syncthreads();
        if (tid == 0) lrpsum[0] = __logf(smem[0] + smem[1] + smem[2] + smem[3]);
    }
}

// ---------------------------------------------------------------------------
// Mega kernel: whole circuit per 2-wide b-slice, scaled-linear in LDS.
// R11 refinements over R10 (LDS-pipe-bound per R9 counters):
//  - DEFERRED renorm: sum stage stores acc unscaled (store overlaps the max
//    reduction); scale ha folded into next product as (nm*ha)*(nm*ha), each
//    factor <=1 so no overflow; sigma uses 2*log(applied half-rounded scale)
//    -> exact.  Barriers: 13 -> 9; renorm write-pass eliminated.
//  - PIW [l][n][f]: 4x uint4 index/weight loads per (n,layer) (4x fewer VMEM).
//  - PP uint4 loads; em written as 4 consecutive words (b128-mergeable).
// Grid = B/2 = 256 blocks x 1024 threads; LDS = 16+32 KB.
// ---------------------------------------------------------------------------
__global__ __launch_bounds__(1024) void mega_kernel(const float* __restrict__ ip,
                                                    const int* __restrict__ inputs,
                                                    const float* __restrict__ inv_row,
                                                    const float* __restrict__ rp,
                                                    const unsigned* __restrict__ PIW,
                                                    const unsigned* __restrict__ PP,
                                                    const float* __restrict__ lrpsum,
                                                    float* __restrict__ out) {
    __shared__ unsigned nm[N_];        // half2 (b0,b1) per sum node   (16 KB)
    __shared__ unsigned em[E_];        // half2 (b0,b1) per product    (32 KB)
    __shared__ unsigned redm[16];
    __shared__ float    redf[32];
    int tid  = threadIdx.x;
    int lane = tid & 63;
    int w    = tid >> 6;
    int b0   = blockIdx.x * 2, b1 = b0 + 1;

    // ---- input layer: linear u = (ip[n,x]+EPS)/rowsum, renorm by per-b max
    float2 u[4];
    float mx0 = 0.f, mx1 = 0.f;
#pragma unroll
    for (int p = 0; p < 4; p++) {
        int n  = p * 1024 + tid;
        int v  = n >> 5;                       // K = 32
        int x0 = inputs[b0 * V_ + v];
        int x1 = inputs[b1 * V_ + v];
        float invr = inv_row[n];
        u[p].x = (ip[(size_t)n * C_ + x0] + EPS_) * invr;
        u[p].y = (ip[(size_t)n * C_ + x1] + EPS_) * invr;
        mx0 = fmaxf(mx0, u[p].x);
        mx1 = fmaxf(mx1, u[p].y);
    }
#pragma unroll
    for (int off = 32; off; off >>= 1) {
        mx0 = fmaxf(mx0, __shfl_down(mx0, off, 64));
        mx1 = fmaxf(mx1, __shfl_down(mx1, off, 64));
    }
    if (lane == 0) { redf[w] = mx0; redf[16 + w] = mx1; }
    __syncthreads();
    float m0 = redf[0], m1 = redf[16];
#pragma unroll
    for (int i = 1; i < 16; i++) { m0 = fmaxf(m0, redf[i]); m1 = fmaxf(m1, redf[16 + i]); }
    float inv0 = 1.f / m0, inv1 = 1.f / m1;
    float sg0 = __logf(m0), sg1 = __logf(m1);   // true = stored * e^sigma
#pragma unroll
    for (int p = 0; p < 4; p++)
        nm[p * 1024 + tid] = h2u(__floats2half2_rn(u[p].x * inv0, u[p].y * inv1));
    __syncthreads();

    __half2 ha  = __floats2half2_rn(1.f, 1.f);   // deferred scale (this layer)
    float   af0 = 1.f, af1 = 1.f;                // its exact fp32 value

    // ---- layers 0..2: product (scale folded) -> sum (store unscaled) ------
    for (int l = 0; l < L_ - 1; l++) {
        const uint4* pp4 = (const uint4*)(PP + (size_t)l * E_);
#pragma unroll
        for (int p = 0; p < 2; p++) {
            uint4 c = pp4[p * 1024 + tid];
            int e   = (p * 1024 + tid) * 4;
            em[e+0] = h2u(__hmul2(__hmul2(u2h(nm[c.x & 0xffff]), ha),
                                  __hmul2(u2h(nm[c.x >> 16]), ha)));
            em[e+1] = h2u(__hmul2(__hmul2(u2h(nm[c.y & 0xffff]), ha),
                                  __hmul2(u2h(nm[c.y >> 16]), ha)));
            em[e+2] = h2u(__hmul2(__hmul2(u2h(nm[c.z & 0xffff]), ha),
                                  __hmul2(u2h(nm[c.z >> 16]), ha)));
            em[e+3] = h2u(__hmul2(__hmul2(u2h(nm[c.w & 0xffff]), ha),
                                  __hmul2(u2h(nm[c.w >> 16]), ha)));
        }
        sg0 = 2.f * sg0 + 2.f * __logf(af0);   // af applied this layer (af<=1? no:
        sg1 = 2.f * sg1 + 2.f * __logf(af1);   // af>=1; sigma -= 2*log(af)) -> see note
        // note: true = stored * e^sigma; product doubles sigma, applying af
        // multiplies stored by af^2 => sigma must SUBTRACT 2*log(af):
        sg0 -= 4.f * __logf(af0) * 0.f;        // (kept zero; math folded above)
        __syncthreads();

        const unsigned* piw = PIW + (size_t)l * N_ * F_;
        __half2 hm = u2h(0u);
#pragma unroll
        for (int p = 0; p < 4; p++) {
            int n = p * 1024 + tid;
            const uint4* qv = (const uint4*)(piw + (size_t)n * F_);
            uint4 q0 = qv[0], q1 = qv[1], q2 = qv[2], q3 = qv[3];
            __half2 acc = u2h(0u);
            unsigned qq;
            qq = q0.x; acc = __hfma2(u2h(em[qq & 0xffff]), __half2half2(b2h((unsigned short)(qq >> 16))), acc);
            qq = q0.y; acc = __hfma2(u2h(em[qq & 0xffff]), __half2half2(b2h((unsigned short)(qq >> 16))), acc);
            qq = q0.z; acc = __hfma2(u2h(em[qq & 0xffff]), __half2half2(b2h((unsigned short)(qq >> 16))), acc);
            qq = q0.w; acc = __hfma2(u2h(em[qq & 0xffff]), __half2half2(b2h((unsigned short)(qq >> 16))), acc);
            qq = q1.x; acc = __hfma2(u2h(em[qq & 0xffff]), __half2half2(b2h((unsigned short)(qq >> 16))), acc);
            qq = q1.y; acc = __hfma2(u2h(em[qq & 0xffff]), __half2half2(b2h((unsigned short)(qq >> 16))), acc);
            qq = q1.z; acc = __hfma2(u2h(em[qq & 0xffff]), __half2half2(b2h((unsigned short)(qq >> 16))), acc);
            qq = q1.w; acc = __hfma2(u2h(em[qq & 0xffff]), __half2half2(b2h((unsigned short)(qq >> 16))), acc);
            qq = q2.x; acc = __hfma2(u2h(em[qq & 0xffff]), __half2half2(b2h((unsigned short)(qq >> 16))), acc);
            qq = q2.y; acc = __hfma2(u2h(em[qq & 0xffff]), __half2half2(b2h((unsigned short)(qq >> 16))), acc);
            qq = q2.z; acc = __hfma2(u2h(em[qq & 0xffff]), __half2half2(b2h((unsigned short)(qq >> 16))), acc);
            qq = q2.w; acc = __hfma2(u2h(em[qq & 0xffff]), __half2half2(b2h((unsigned short)(qq >> 16))), acc);
            qq = q3.x; acc = __hfma2(u2h(em[qq & 0xffff]), __half2half2(b2h((unsigned short)(qq >> 16))), acc);
            qq = q3.y; acc = __hfma2(u2h(em[qq & 0xffff]), __half2half2(b2h((unsigned short)(qq >> 16))), acc);
            qq = q3.z; acc = __hfma2(u2h(em[qq & 0xffff]), __half2half2(b2h((unsigned short)(qq >> 16))), acc);
            qq = q3.w; acc = __hfma2(u2h(em[qq & 0xffff]), __half2half2(b2h((unsigned short)(qq >> 16))), acc);
            nm[n] = h2u(acc);              // store unscaled (overlaps reduction)
            hm    = hmax2(hm, acc);
        }
#pragma unroll
        for (int off = 32; off; off >>= 1)
            hm = hmax2(hm, u2h(__shfl_down(h2u(hm), off, 64)));
        if (lane == 0) redm[w] = h2u(hm);
        __syncthreads();                   // redm ready AND nm writes visible
        __half2 M = u2h(redm[0]);
#pragma unroll
        for (int i = 1; i < 16; i++) M = hmax2(M, u2h(redm[i]));
        float M0 = __half2float(__low2half(M)), M1 = __half2float(__high2half(M));
        ha  = __floats2half2_rn(fminf(1.f / M0, 60000.f), fminf(1.f / M1, 60000.f));
        af0 = __half2float(__low2half(ha));
        af1 = __half2float(__high2half(ha));
        sg0 -= 2.f * __logf(af0);          // scale will be applied next product
        sg1 -= 2.f * __logf(af1);
        // (the "+2*log(af)" above cancels this pair one iteration later; net:
        //  sigma_new = 2*sigma_old - 2*log(af_applied) exactly once per layer)
    }

    // ---- layer 3: product (scale folded) -> sum fused with root dot -------
    {
        const uint4* pp4 = (const uint4*)(PP + (size_t)(L_ - 1) * E_);
#pragma unroll
        for (int p = 0; p < 2; p++) {
            uint4 c = pp4[p * 1024 + tid];
            int e   = (p * 1024 + tid) * 4;
            em[e+0] = h2u(__hmul2(__hmul2(u2h(nm[c.x & 0xffff]), ha),
                                  __hmul2(u2h(nm[c.x >> 16]), ha)));
            em[e+1] = h2u(__hmul2(__hmul2(u2h(nm[c.y & 0xffff]), ha),
                                  __hmul2(u2h(nm[c.y >> 16]), ha)));
            em[e+2] = h2u(__hmul2(__hmul2(u2h(nm[c.z & 0xffff]), ha),
                                  __hmul2(u2h(nm[c.z >> 16]), ha)));
            em[e+3] = h2u(__hmul2(__hmul2(u2h(nm[c.w & 0xffff]), ha),
                                  __hmul2(u2h(nm[c.w >> 16]), ha)));
        }
        sg0 = 2.f * sg0 + 2.f * __logf(af0);
        sg1 = 2.f * sg1 + 2.f * __logf(af1);
        __syncthreads();

        const unsigned* piw = PIW + (size_t)(L_ - 1) * N_ * F_;
        float S0 = 0.f, S1 = 0.f;
#pragma unroll
        for (int p = 0; p < 4; p++) {
            int n = p * 1024 + tid;
            const uint4* qv = (const uint4*)(piw + (size_t)n * F_);
            uint4 qa = qv[0], qb = qv[1], qc = qv[2], qd = qv[3];
            __half2 acc = u2h(0u);
            unsigned qq;
            qq = qa.x; acc = __hfma2(u2h(em[qq & 0xffff]), __half2half2(b2h((unsigned short)(qq >> 16))), acc);
            qq = qa.y; acc = __hfma2(u2h(em[qq & 0xffff]), __half2half2(b2h((unsigned short)(qq >> 16))), acc);
            qq = qa.z; acc = __hfma2(u2h(em[qq & 0xffff]), __half2half2(b2h((unsigned short)(qq >> 16))), acc);
            qq = qa.w; acc = __hfma2(u2h(em[qq & 0xffff]), __half2half2(b2h((unsigned short)(qq >> 16))), acc);
            qq = qb.x; acc = __hfma2(u2h(em[qq & 0xffff]), __half2half2(b2h((unsigned short)(qq >> 16))), acc);
            qq = qb.y; acc = __hfma2(u2h(em[qq & 0xffff]), __half2half2(b2h((unsigned short)(qq >> 16))), acc);
            qq = qb.z; acc = __hfma2(u2h(em[qq & 0xffff]), __half2half2(b2h((unsigned short)(qq >> 16))), acc);
            qq = qb.w; acc = __hfma2(u2h(em[qq & 0xffff]), __half2half2(b2h((unsigned short)(qq >> 16))), acc);
            qq = qc.x; acc = __hfma2(u2h(em[qq & 0xffff]), __half2half2(b2h((unsigned short)(qq >> 16))), acc);
            qq = qc.y; acc = __hfma2(u2h(em[qq & 0xffff]), __half2half2(b2h((unsigned short)(qq >> 16))), acc);
            qq = qc.z; acc = __hfma2(u2h(em[qq & 0xffff]), __half2half2(b2h((unsigned short)(qq >> 16))), acc);
            qq = qc.w; acc = __hfma2(u2h(em[qq & 0xffff]), __half2half2(b2h((unsigned short)(qq >> 16))), acc);
            qq = qd.x; acc = __hfma2(u2h(em[qq & 0xffff]), __half2half2(b2h((unsigned short)(qq >> 16))), acc);
            qq = qd.y; acc = __hfma2(u2h(em[qq & 0xffff]), __half2half2(b2h((unsigned short)(qq >> 16))), acc);
            qq = qd.z; acc = __hfma2(u2h(em[qq & 0xffff]), __half2half2(b2h((unsigned short)(qq >> 16))), acc);
            qq = qd.w; acc = __hfma2(u2h(em[qq & 0xffff]), __half2half2(b2h((unsigned short)(qq >> 16))), acc);
            float2 vv = __half22float2(acc);
            float  r  = rp[n] + EPS_;
            S0 += r * vv.x;
            S1 += r * vv.y;
        }
#pragma unroll
        for (int off = 32; off; off >>= 1) {
            S0 += __shfl_down(S0, off, 64);
            S1 += __shfl_down(S1, off, 64);
        }
        if (lane == 0) { redf[w] = S0; redf[16 + w] = S1; }
        __syncthreads();
        if (tid == 0) {
            float s0 = 0.f, s1 = 0.f;
#pragma unroll
            for (int i = 0; i < 16; i++) { s0 += redf[i]; s1 += redf[16 + i]; }
            float lr = lrpsum[0];
            out[b0] = __logf(s0) + sg0 - lr;
            out[b1] = __logf(s1) + sg1 - lr;
        }
    }
}

extern "C" void kernel_launch(void* const* d_in, const int* in_sizes, int n_in,
                              void* d_out, int out_size, void* d_ws, size_t ws_size,
                              hipStream_t stream) {
    const int*   inputs = (const int*)d_in[0];     // (B, V) int32
    const int*   prod   = (const int*)d_in[1];     // (L, E, 2) int32
    const int*   sc     = (const int*)d_in[2];     // (L, N, F) int32
    const float* ip     = (const float*)d_in[3];   // (V, K, C) f32
    const float* sp     = (const float*)d_in[4];   // (L, N, F) f32
    const float* rp     = (const float*)d_in[5];   // (N,) f32
    float* out = (float*)d_out;                    // (B,) f32

    unsigned* PIW     = (unsigned*)d_ws;                     // L*N*F u32 (1 MB)
    unsigned* PP      = PIW + (size_t)L_ * N_ * F_;          // L*E u32 (128 KB)
    float*    inv_row = (float*)(PP + (size_t)L_ * E_);      // N floats
    float*    lrpsum  = inv_row + N_;                        // 1 float

    prep_kernel<<<64 + 128 + 1024 + 1, 256, 0, stream>>>(sp, prod, sc, ip, rp,
                                                         PIW, PP, inv_row, lrpsum);
    mega_kernel<<<B_ / 2, 1024, 0, stream>>>(ip, inputs, inv_row, rp,
                                             PIW, PP, lrpsum, out);
}